// Round 5
// baseline (23793.768 us; speedup 1.0000x reference)
//
#include <hip/hip_runtime.h>
#include <math.h>

#define BATCH   64
#define SEQLEN  128
#define EMBED   512
#define HID     1024
#define NSTEP   127
#define OUT0    65
#define NOUT    62
#define NBLK    512
#define NTHR    512

// LDS layout (floats) for lstm_persist:
//   wlds [uu 2][k 1536][gate 4] = 12288 @ 0        (48 KB, persistent)
//   red  phaseA 2048 @ 12288, phaseB 1024 @ 14336, phaseC 512 @ 15360
//   c    128 @ 15872  (persistent c-state for this block's 2 units)
#define REDA_OFF 12288
#define REDB_OFF 14336
#define REDC_OFF 15360
#define C_OFF    15872
#define LDS_FLOATS 16000   // 64000 B

__device__ __forceinline__ float sigmoidf_(float x) { return 1.f / (1.f + expf(-x)); }

__device__ __forceinline__ void grid_sync(int* bar, int target) {
    __threadfence();
    __syncthreads();
    if (threadIdx.x == 0) {
        __hip_atomic_fetch_add(bar, 1, __ATOMIC_RELEASE, __HIP_MEMORY_SCOPE_AGENT);
        while (__hip_atomic_load(bar, __ATOMIC_ACQUIRE, __HIP_MEMORY_SCOPE_AGENT) < target) {
            __builtin_amdgcn_s_sleep(8);
        }
    }
    __syncthreads();
    __threadfence();
}

// Transpose h0/c0 ([b][u]) into [u][b] working layout.
__global__ __launch_bounds__(256) void init_state(
    const float* __restrict__ h0, const float* __restrict__ c0,
    float* __restrict__ hT, float* __restrict__ cT)
{
    int id = blockIdx.x * 256 + threadIdx.x;   // u*64+b
    int u = id >> 6, b = id & 63;
    hT[id] = h0[b * HID + u];
    cT[id] = c0[b * HID + u];
}

// Build xT[t][k][b] = embed[prob[b][t]][k] (one-time gather+transpose).
__global__ __launch_bounds__(256) void embed_transpose(
    const int* __restrict__ prob, const float* __restrict__ embed,
    float* __restrict__ xT)
{
    __shared__ float xe[64 * 132];
    int t = blockIdx.x;
    int tid = threadIdx.x;
    for (int kt = 0; kt < 4; ++kt) {
        #pragma unroll
        for (int i = 0; i < 8; ++i) {
            int id = tid + i * 256;
            int b  = id >> 5;
            int k4 = id & 31;
            int tok = prob[b * SEQLEN + t];
            float4 v = *(const float4*)(embed + (size_t)tok * EMBED + kt * 128 + k4 * 4);
            *(float4*)(&xe[b * 132 + k4 * 4]) = v;
        }
        __syncthreads();
        #pragma unroll
        for (int i = 0; i < 8; ++i) {
            int id = tid + i * 256;
            int kl = id >> 4;
            int b4 = id & 15;
            float4 v;
            v.x = xe[(b4 * 4 + 0) * 132 + kl];
            v.y = xe[(b4 * 4 + 1) * 132 + kl];
            v.z = xe[(b4 * 4 + 2) * 132 + kl];
            v.w = xe[(b4 * 4 + 3) * 132 + kl];
            *(float4*)(&xT[((size_t)t * EMBED + kt * 128 + kl) * 64 + b4 * 4]) = v;
        }
        __syncthreads();
    }
}

// ===================== persistent path =====================
// 512 blocks x 512 threads (2 blocks/CU), cooperative launch.
// Block bid owns units u0=bid*2, u0+1; weights LDS-resident for all 127 steps.
// Wave ksl (0..7) = K-slice of 192; lane = batch b.
__global__ __launch_bounds__(NTHR, 4) void lstm_persist(
    const float* __restrict__ xT, float* __restrict__ hb0, float* __restrict__ hb1,
    const float* __restrict__ cT,
    const float* __restrict__ w_ih, const float* __restrict__ w_hh,
    const float* __restrict__ b_ih, const float* __restrict__ b_hh,
    const float* __restrict__ w_ans, float* __restrict__ pout,
    int* __restrict__ bar)
{
    __shared__ float lds[LDS_FLOATS];
    const int tid = threadIdx.x;
    const int bid = blockIdx.x;
    const int b   = tid & 63;
    const int ksl = __builtin_amdgcn_readfirstlane(tid >> 6);  // 0..7
    const int u0  = bid * 2;

    // one-time: weights -> LDS  [uu][k][gate]
    for (int idx = tid; idx < 12288; idx += NTHR) {
        int r  = idx / 1536;          // 0..7
        int k  = idx - r * 1536;
        int uu = r & 1, gate = r >> 1;
        int row = gate * HID + u0 + uu;
        float v = (k < EMBED) ? w_ih[(size_t)row * EMBED + k]
                              : w_hh[(size_t)row * HID + (k - EMBED)];
        lds[(uu * 1536 + k) * 4 + gate] = v;
    }
    if (tid < 128) lds[C_OFF + tid] = cT[u0 * 64 + tid];

    float bias[2][4], wans[2];
    #pragma unroll
    for (int uu = 0; uu < 2; ++uu) {
        #pragma unroll
        for (int j = 0; j < 4; ++j) {
            int rj = j * HID + u0 + uu;
            bias[uu][j] = b_ih[rj] + b_hh[rj];
        }
        wans[uu] = w_ans[u0 + uu];
    }
    __syncthreads();

    for (int t = 0; t < NSTEP; ++t) {
        const float* xt   = xT + (size_t)t * EMBED * 64;
        const float* ht   = (t & 1) ? hb1 : hb0;
        float* hn_buf     = (t & 1) ? hb0 : hb1;

        float acc[2][4];
        #pragma unroll
        for (int uu = 0; uu < 2; ++uu)
            #pragma unroll
            for (int j = 0; j < 4; ++j) acc[uu][j] = 0.f;

        const int k0 = ksl * 192;
        #pragma unroll 2
        for (int g = 0; g < 48; ++g) {
            const int k = k0 + g * 4;
            const float* src = (k < EMBED) ? (xt + (size_t)k * 64)
                                           : (ht + (size_t)(k - EMBED) * 64);
            float xv[4];
            #pragma unroll
            for (int i = 0; i < 4; ++i) xv[i] = src[i * 64 + b];
            #pragma unroll
            for (int i = 0; i < 4; ++i) {
                float4 wa = *(const float4*)&lds[(0 * 1536 + k + i) * 4];
                float4 wb = *(const float4*)&lds[(1 * 1536 + k + i) * 4];
                acc[0][0] = fmaf(wa.x, xv[i], acc[0][0]);
                acc[0][1] = fmaf(wa.y, xv[i], acc[0][1]);
                acc[0][2] = fmaf(wa.z, xv[i], acc[0][2]);
                acc[0][3] = fmaf(wa.w, xv[i], acc[0][3]);
                acc[1][0] = fmaf(wb.x, xv[i], acc[1][0]);
                acc[1][1] = fmaf(wb.y, xv[i], acc[1][1]);
                acc[1][2] = fmaf(wb.z, xv[i], acc[1][2]);
                acc[1][3] = fmaf(wb.w, xv[i], acc[1][3]);
            }
        }

        // tree reduction 8 -> 4 -> 2 -> 1 waves
        if (ksl >= 4) {
            #pragma unroll
            for (int uu = 0; uu < 2; ++uu)
                #pragma unroll
                for (int j = 0; j < 4; ++j)
                    lds[REDA_OFF + (((ksl - 4) * 8) + uu * 4 + j) * 64 + b] = acc[uu][j];
        }
        __syncthreads();
        if (ksl < 4) {
            #pragma unroll
            for (int uu = 0; uu < 2; ++uu)
                #pragma unroll
                for (int j = 0; j < 4; ++j)
                    acc[uu][j] += lds[REDA_OFF + ((ksl * 8) + uu * 4 + j) * 64 + b];
        }
        if (ksl == 2 || ksl == 3) {
            #pragma unroll
            for (int uu = 0; uu < 2; ++uu)
                #pragma unroll
                for (int j = 0; j < 4; ++j)
                    lds[REDB_OFF + (((ksl - 2) * 8) + uu * 4 + j) * 64 + b] = acc[uu][j];
        }
        __syncthreads();
        if (ksl < 2) {
            #pragma unroll
            for (int uu = 0; uu < 2; ++uu)
                #pragma unroll
                for (int j = 0; j < 4; ++j)
                    acc[uu][j] += lds[REDB_OFF + ((ksl * 8) + uu * 4 + j) * 64 + b];
        }
        if (ksl == 1) {
            #pragma unroll
            for (int uu = 0; uu < 2; ++uu)
                #pragma unroll
                for (int j = 0; j < 4; ++j)
                    lds[REDC_OFF + (uu * 4 + j) * 64 + b] = acc[uu][j];
        }
        __syncthreads();
        if (ksl == 0) {
            float hvals[2];
            #pragma unroll
            for (int uu = 0; uu < 2; ++uu) {
                #pragma unroll
                for (int j = 0; j < 4; ++j)
                    acc[uu][j] += lds[REDC_OFF + (uu * 4 + j) * 64 + b];
                float i_g = sigmoidf_(acc[uu][0] + bias[uu][0]);
                float f_g = sigmoidf_(acc[uu][1] + bias[uu][1]);
                float g_g = tanhf   (acc[uu][2] + bias[uu][2]);
                float o_g = sigmoidf_(acc[uu][3] + bias[uu][3]);
                float c_old = lds[C_OFF + uu * 64 + b];
                float c_new = f_g * c_old + i_g * g_g;
                float h_new = o_g * tanhf(c_new);
                lds[C_OFF + uu * 64 + b] = c_new;
                hn_buf[(u0 + uu) * 64 + b] = h_new;
                hvals[uu] = h_new;
            }
            if (t >= OUT0) {
                pout[((size_t)(t - OUT0) * NBLK + bid) * 64 + b] =
                    hvals[0] * wans[0] + hvals[1] * wans[1];
            }
        }

        grid_sync(bar, NBLK * (t + 1));
    }
}

// out[b][col] = sum over 512 block partials + bias.  (persist layout)
__global__ __launch_bounds__(256) void finalize_persist(
    const float* __restrict__ pout, const float* __restrict__ b_ans,
    float* __restrict__ out)
{
    __shared__ float r[256];
    int col = blockIdx.x;
    int tid = threadIdx.x;
    int b = tid & 63, q = tid >> 6;
    float s = 0.f;
    for (int i = q; i < NBLK; i += 4)
        s += pout[((size_t)col * NBLK + i) * 64 + b];
    r[tid] = s;
    __syncthreads();
    if (tid < 64)
        out[tid * NOUT + col] = r[tid] + r[64 + tid] + r[128 + tid] + r[192 + tid]
                              + b_ans[0];
}

// ===================== fallback path (round-3 proven) =====================
#define F_HEADOFF 4096
__global__ __launch_bounds__(1024, 4) void lstm_step_fb(
    const float* __restrict__ xT, const float* __restrict__ hT_in,
    float* __restrict__ hT_out, float* __restrict__ cT,
    const float* __restrict__ w_ih, const float* __restrict__ w_hh,
    const float* __restrict__ b_ih, const float* __restrict__ b_hh,
    const float* __restrict__ w_ans, float* __restrict__ pout, int t)
{
    __shared__ float lds[F_HEADOFF + 256];
    const int tid = threadIdx.x;
    const int bid = blockIdx.x;
    const int b   = tid & 63;
    const int ws  = __builtin_amdgcn_readfirstlane(tid >> 6);
    const int uu  = ws & 3;
    const int ksl = ws >> 2;
    const int u   = bid * 4 + uu;

    const float* wr_i[4];
    const float* wr_h[4];
    #pragma unroll
    for (int j = 0; j < 4; ++j) {
        wr_i[j] = w_ih + (size_t)(j * HID + u) * EMBED;
        wr_h[j] = w_hh + (size_t)(j * HID + u) * HID;
    }
    float acc[4];
    acc[0] = acc[1] = acc[2] = acc[3] = 0.f;
    {
        const float* xt = xT + (size_t)t * EMBED * 64;
        const int k0 = ksl * 128;
        #pragma unroll 4
        for (int g = 0; g < 32; ++g) {
            const int k = k0 + g * 4;
            float4 wv0 = *(const float4*)(wr_i[0] + k);
            float4 wv1 = *(const float4*)(wr_i[1] + k);
            float4 wv2 = *(const float4*)(wr_i[2] + k);
            float4 wv3 = *(const float4*)(wr_i[3] + k);
            float x0 = xt[(k + 0) * 64 + b];
            float x1 = xt[(k + 1) * 64 + b];
            float x2 = xt[(k + 2) * 64 + b];
            float x3 = xt[(k + 3) * 64 + b];
            acc[0] = fmaf(wv0.x, x0, acc[0]); acc[0] = fmaf(wv0.y, x1, acc[0]);
            acc[0] = fmaf(wv0.z, x2, acc[0]); acc[0] = fmaf(wv0.w, x3, acc[0]);
            acc[1] = fmaf(wv1.x, x0, acc[1]); acc[1] = fmaf(wv1.y, x1, acc[1]);
            acc[1] = fmaf(wv1.z, x2, acc[1]); acc[1] = fmaf(wv1.w, x3, acc[1]);
            acc[2] = fmaf(wv2.x, x0, acc[2]); acc[2] = fmaf(wv2.y, x1, acc[2]);
            acc[2] = fmaf(wv2.z, x2, acc[2]); acc[2] = fmaf(wv2.w, x3, acc[2]);
            acc[3] = fmaf(wv3.x, x0, acc[3]); acc[3] = fmaf(wv3.y, x1, acc[3]);
            acc[3] = fmaf(wv3.z, x2, acc[3]); acc[3] = fmaf(wv3.w, x3, acc[3]);
        }
    }
    {
        const int k0 = ksl * 256;
        #pragma unroll 4
        for (int g = 0; g < 64; ++g) {
            const int k = k0 + g * 4;
            float4 wv0 = *(const float4*)(wr_h[0] + k);
            float4 wv1 = *(const float4*)(wr_h[1] + k);
            float4 wv2 = *(const float4*)(wr_h[2] + k);
            float4 wv3 = *(const float4*)(wr_h[3] + k);
            float x0 = hT_in[(k + 0) * 64 + b];
            float x1 = hT_in[(k + 1) * 64 + b];
            float x2 = hT_in[(k + 2) * 64 + b];
            float x3 = hT_in[(k + 3) * 64 + b];
            acc[0] = fmaf(wv0.x, x0, acc[0]); acc[0] = fmaf(wv0.y, x1, acc[0]);
            acc[0] = fmaf(wv0.z, x2, acc[0]); acc[0] = fmaf(wv0.w, x3, acc[0]);
            acc[1] = fmaf(wv1.x, x0, acc[1]); acc[1] = fmaf(wv1.y, x1, acc[1]);
            acc[1] = fmaf(wv1.z, x2, acc[1]); acc[1] = fmaf(wv1.w, x3, acc[1]);
            acc[2] = fmaf(wv2.x, x0, acc[2]); acc[2] = fmaf(wv2.y, x1, acc[2]);
            acc[2] = fmaf(wv2.z, x2, acc[2]); acc[2] = fmaf(wv2.w, x3, acc[2]);
            acc[3] = fmaf(wv3.x, x0, acc[3]); acc[3] = fmaf(wv3.y, x1, acc[3]);
            acc[3] = fmaf(wv3.z, x2, acc[3]); acc[3] = fmaf(wv3.w, x3, acc[3]);
        }
    }
    #pragma unroll
    for (int j = 0; j < 4; ++j)
        lds[((ksl * 4 + uu) * 4 + j) * 64 + b] = acc[j];
    __syncthreads();
    if (tid < 256) {
        int b2  = tid & 63;
        int uu2 = tid >> 6;
        int u2  = bid * 4 + uu2;
        float s[4];
        #pragma unroll
        for (int j = 0; j < 4; ++j) {
            s[j] = lds[((0 * 4 + uu2) * 4 + j) * 64 + b2]
                 + lds[((1 * 4 + uu2) * 4 + j) * 64 + b2]
                 + lds[((2 * 4 + uu2) * 4 + j) * 64 + b2]
                 + lds[((3 * 4 + uu2) * 4 + j) * 64 + b2];
            int rj = j * HID + u2;
            s[j] += b_ih[rj] + b_hh[rj];
        }
        float ig = sigmoidf_(s[0]);
        float fg = sigmoidf_(s[1]);
        float gg = tanhf(s[2]);
        float og = sigmoidf_(s[3]);
        float cn = fg * cT[u2 * 64 + b2] + ig * gg;
        float hn = og * tanhf(cn);
        cT[u2 * 64 + b2]     = cn;
        hT_out[u2 * 64 + b2] = hn;
        lds[F_HEADOFF + uu2 * 64 + b2] = hn * w_ans[u2];
    }
    __syncthreads();
    if (t >= OUT0 && tid < 64) {
        float sum = lds[F_HEADOFF + tid]       + lds[F_HEADOFF + 64 + tid]
                  + lds[F_HEADOFF + 128 + tid] + lds[F_HEADOFF + 192 + tid];
        pout[((size_t)((t - OUT0) * 64 + tid)) * 256 + bid] = sum;
    }
}

__global__ __launch_bounds__(64) void finalize_fb(
    const float* __restrict__ pout, const float* __restrict__ b_ans,
    float* __restrict__ out)
{
    int blk  = blockIdx.x;
    int col  = blk >> 6;
    int bb   = blk & 63;
    int lane = threadIdx.x;
    const float* p = pout + (size_t)(col * 64 + bb) * 256;
    float s = p[lane] + p[lane + 64] + p[lane + 128] + p[lane + 192];
    #pragma unroll
    for (int off = 32; off > 0; off >>= 1) s += __shfl_down(s, off);
    if (lane == 0) out[bb * NOUT + col] = s + b_ans[0];
}

extern "C" void kernel_launch(void* const* d_in, const int* in_sizes, int n_in,
                              void* d_out, int out_size, void* d_ws, size_t ws_size,
                              hipStream_t stream)
{
    const int*   prob  = (const int*)  d_in[0];
    const float* embed = (const float*)d_in[2];
    const float* w_ih  = (const float*)d_in[3];
    const float* w_hh  = (const float*)d_in[4];
    const float* b_ih  = (const float*)d_in[5];
    const float* b_hh  = (const float*)d_in[6];
    const float* w_ans = (const float*)d_in[7];
    const float* b_ans = (const float*)d_in[8];
    const float* h0    = (const float*)d_in[9];
    const float* c0    = (const float*)d_in[10];

    float* ws   = (float*)d_ws;
    float* hT0  = ws;                          // 65536
    float* hT1  = ws + 65536;                  // 65536
    float* cT   = ws + 131072;                 // 65536
    float* pout = ws + 196608;                 // max(62*512*64, 62*64*256) = 2,031,616
    float* xT   = ws + 2228224;                // 127*512*64 = 4,161,536
    int*   bar  = (int*)(ws + 6389760);

    hipMemsetAsync(bar, 0, sizeof(int), stream);
    init_state<<<256, 256, 0, stream>>>(h0, c0, hT0, cT);
    embed_transpose<<<NSTEP, 256, 0, stream>>>(prob, embed, xT);

    void* args[] = {
        (void*)&xT, (void*)&hT0, (void*)&hT1, (void*)&cT,
        (void*)&w_ih, (void*)&w_hh, (void*)&b_ih, (void*)&b_hh,
        (void*)&w_ans, (void*)&pout, (void*)&bar
    };
    hipError_t err = hipLaunchCooperativeKernel((const void*)lstm_persist,
                                                dim3(NBLK), dim3(NTHR),
                                                args, 0, stream);
    if (err == hipSuccess) {
        finalize_persist<<<NOUT, 256, 0, stream>>>(pout, b_ans, (float*)d_out);
    } else {
        // fallback: proven per-step path
        for (int t = 0; t < NSTEP; ++t) {
            float* hin  = (t & 1) ? hT1 : hT0;
            float* hout = (t & 1) ? hT0 : hT1;
            lstm_step_fb<<<256, 1024, 0, stream>>>(xT, hin, hout, cT, w_ih, w_hh,
                                                   b_ih, b_hh, w_ans, pout, t);
        }
        finalize_fb<<<NOUT * 64, 64, 0, stream>>>(pout, b_ans, (float*)d_out);
    }
}

// Round 6
// 6459.625 us; speedup vs baseline: 3.6835x; 3.6835x over previous
//
#include <hip/hip_runtime.h>
#include <math.h>

#define BATCH   64
#define SEQLEN  128
#define EMBED   512
#define HID     1024
#define NSTEP   127
#define OUT0    65
#define NOUT    62
#define NBLK    512
#define NTHR    512

// LDS layout (floats) for lstm_persist:
//   wlds [uu 2][k 1536][gate 4] = 12288 @ 0        (48 KB, persistent)
//   red  phaseA 2048 @ 12288, phaseB 1024 @ 14336, phaseC 512 @ 15360
//   c    128 @ 15872  (persistent c-state for this block's 2 units)
#define REDA_OFF 12288
#define REDB_OFF 14336
#define REDC_OFF 15360
#define C_OFF    15872
#define LDS_FLOATS 16000   // 64000 B

__device__ __forceinline__ float sigmoidf_(float x) { return 1.f / (1.f + expf(-x)); }

// Grid barrier. Round-5 lesson: an ACQUIRE agent-scope load in the spin loop
// emits a full per-XCD L2 invalidate PER ITERATION -> ~180us/step. Fix:
// relaxed spin (plain sc1 load), single thread-0 release fence before arrive
// and single thread-0 acquire fence (buffer_inv) after the spin exits.
__device__ __forceinline__ void grid_sync(int* bar, int target) {
    __syncthreads();   // drains vmcnt(0) for ALL waves before t0 proceeds
    if (threadIdx.x == 0) {
        __threadfence();   // release: L2 writeback (thread-0 only, once/step)
        __hip_atomic_fetch_add(bar, 1, __ATOMIC_RELAXED, __HIP_MEMORY_SCOPE_AGENT);
        while (__hip_atomic_load(bar, __ATOMIC_RELAXED, __HIP_MEMORY_SCOPE_AGENT) < target)
            __builtin_amdgcn_s_sleep(2);
        __builtin_amdgcn_fence(__ATOMIC_ACQUIRE, "agent");  // single L2 inv
    }
    __syncthreads();
}

// Transpose h0/c0 ([b][u]) into [u][b] working layout.
__global__ __launch_bounds__(256) void init_state(
    const float* __restrict__ h0, const float* __restrict__ c0,
    float* __restrict__ hT, float* __restrict__ cT)
{
    int id = blockIdx.x * 256 + threadIdx.x;   // u*64+b
    int u = id >> 6, b = id & 63;
    hT[id] = h0[b * HID + u];
    cT[id] = c0[b * HID + u];
}

// Build xT[t][k][b] = embed[prob[b][t]][k] (one-time gather+transpose).
__global__ __launch_bounds__(256) void embed_transpose(
    const int* __restrict__ prob, const float* __restrict__ embed,
    float* __restrict__ xT)
{
    __shared__ float xe[64 * 132];
    int t = blockIdx.x;
    int tid = threadIdx.x;
    for (int kt = 0; kt < 4; ++kt) {
        #pragma unroll
        for (int i = 0; i < 8; ++i) {
            int id = tid + i * 256;
            int b  = id >> 5;
            int k4 = id & 31;
            int tok = prob[b * SEQLEN + t];
            float4 v = *(const float4*)(embed + (size_t)tok * EMBED + kt * 128 + k4 * 4);
            *(float4*)(&xe[b * 132 + k4 * 4]) = v;
        }
        __syncthreads();
        #pragma unroll
        for (int i = 0; i < 8; ++i) {
            int id = tid + i * 256;
            int kl = id >> 4;
            int b4 = id & 15;
            float4 v;
            v.x = xe[(b4 * 4 + 0) * 132 + kl];
            v.y = xe[(b4 * 4 + 1) * 132 + kl];
            v.z = xe[(b4 * 4 + 2) * 132 + kl];
            v.w = xe[(b4 * 4 + 3) * 132 + kl];
            *(float4*)(&xT[((size_t)t * EMBED + kt * 128 + kl) * 64 + b4 * 4]) = v;
        }
        __syncthreads();
    }
}

// ===================== persistent path =====================
// 512 blocks x 512 threads (2 blocks/CU), cooperative launch.
// Block bid owns units u0=bid*2, u0+1; weights LDS-resident for all 127 steps.
// Wave ksl (0..7) = K-slice of 192; lane = batch b.
__global__ __launch_bounds__(NTHR, 4) void lstm_persist(
    const float* __restrict__ xT, float* __restrict__ hb0, float* __restrict__ hb1,
    const float* __restrict__ cT,
    const float* __restrict__ w_ih, const float* __restrict__ w_hh,
    const float* __restrict__ b_ih, const float* __restrict__ b_hh,
    const float* __restrict__ w_ans, float* __restrict__ pout,
    int* __restrict__ bar)
{
    __shared__ float lds[LDS_FLOATS];
    const int tid = threadIdx.x;
    const int bid = blockIdx.x;
    const int b   = tid & 63;
    const int ksl = __builtin_amdgcn_readfirstlane(tid >> 6);  // 0..7
    const int u0  = bid * 2;

    // one-time: weights -> LDS  [uu][k][gate]
    for (int idx = tid; idx < 12288; idx += NTHR) {
        int r  = idx / 1536;          // 0..7
        int k  = idx - r * 1536;
        int uu = r & 1, gate = r >> 1;
        int row = gate * HID + u0 + uu;
        float v = (k < EMBED) ? w_ih[(size_t)row * EMBED + k]
                              : w_hh[(size_t)row * HID + (k - EMBED)];
        lds[(uu * 1536 + k) * 4 + gate] = v;
    }
    if (tid < 128) lds[C_OFF + tid] = cT[u0 * 64 + tid];

    float bias[2][4], wans[2];
    #pragma unroll
    for (int uu = 0; uu < 2; ++uu) {
        #pragma unroll
        for (int j = 0; j < 4; ++j) {
            int rj = j * HID + u0 + uu;
            bias[uu][j] = b_ih[rj] + b_hh[rj];
        }
        wans[uu] = w_ans[u0 + uu];
    }
    __syncthreads();

    for (int t = 0; t < NSTEP; ++t) {
        const float* xt   = xT + (size_t)t * EMBED * 64;
        const float* ht   = (t & 1) ? hb1 : hb0;
        float* hn_buf     = (t & 1) ? hb0 : hb1;

        float acc[2][4];
        #pragma unroll
        for (int uu = 0; uu < 2; ++uu)
            #pragma unroll
            for (int j = 0; j < 4; ++j) acc[uu][j] = 0.f;

        const int k0 = ksl * 192;
        #pragma unroll 2
        for (int g = 0; g < 48; ++g) {
            const int k = k0 + g * 4;
            const float* src = (k < EMBED) ? (xt + (size_t)k * 64)
                                           : (ht + (size_t)(k - EMBED) * 64);
            float xv[4];
            #pragma unroll
            for (int i = 0; i < 4; ++i) xv[i] = src[i * 64 + b];
            #pragma unroll
            for (int i = 0; i < 4; ++i) {
                float4 wa = *(const float4*)&lds[(0 * 1536 + k + i) * 4];
                float4 wb = *(const float4*)&lds[(1 * 1536 + k + i) * 4];
                acc[0][0] = fmaf(wa.x, xv[i], acc[0][0]);
                acc[0][1] = fmaf(wa.y, xv[i], acc[0][1]);
                acc[0][2] = fmaf(wa.z, xv[i], acc[0][2]);
                acc[0][3] = fmaf(wa.w, xv[i], acc[0][3]);
                acc[1][0] = fmaf(wb.x, xv[i], acc[1][0]);
                acc[1][1] = fmaf(wb.y, xv[i], acc[1][1]);
                acc[1][2] = fmaf(wb.z, xv[i], acc[1][2]);
                acc[1][3] = fmaf(wb.w, xv[i], acc[1][3]);
            }
        }

        // tree reduction 8 -> 4 -> 2 -> 1 waves
        if (ksl >= 4) {
            #pragma unroll
            for (int uu = 0; uu < 2; ++uu)
                #pragma unroll
                for (int j = 0; j < 4; ++j)
                    lds[REDA_OFF + (((ksl - 4) * 8) + uu * 4 + j) * 64 + b] = acc[uu][j];
        }
        __syncthreads();
        if (ksl < 4) {
            #pragma unroll
            for (int uu = 0; uu < 2; ++uu)
                #pragma unroll
                for (int j = 0; j < 4; ++j)
                    acc[uu][j] += lds[REDA_OFF + ((ksl * 8) + uu * 4 + j) * 64 + b];
        }
        if (ksl == 2 || ksl == 3) {
            #pragma unroll
            for (int uu = 0; uu < 2; ++uu)
                #pragma unroll
                for (int j = 0; j < 4; ++j)
                    lds[REDB_OFF + (((ksl - 2) * 8) + uu * 4 + j) * 64 + b] = acc[uu][j];
        }
        __syncthreads();
        if (ksl < 2) {
            #pragma unroll
            for (int uu = 0; uu < 2; ++uu)
                #pragma unroll
                for (int j = 0; j < 4; ++j)
                    acc[uu][j] += lds[REDB_OFF + ((ksl * 8) + uu * 4 + j) * 64 + b];
        }
        if (ksl == 1) {
            #pragma unroll
            for (int uu = 0; uu < 2; ++uu)
                #pragma unroll
                for (int j = 0; j < 4; ++j)
                    lds[REDC_OFF + (uu * 4 + j) * 64 + b] = acc[uu][j];
        }
        __syncthreads();
        if (ksl == 0) {
            float hvals[2];
            #pragma unroll
            for (int uu = 0; uu < 2; ++uu) {
                #pragma unroll
                for (int j = 0; j < 4; ++j)
                    acc[uu][j] += lds[REDC_OFF + (uu * 4 + j) * 64 + b];
                float i_g = sigmoidf_(acc[uu][0] + bias[uu][0]);
                float f_g = sigmoidf_(acc[uu][1] + bias[uu][1]);
                float g_g = tanhf   (acc[uu][2] + bias[uu][2]);
                float o_g = sigmoidf_(acc[uu][3] + bias[uu][3]);
                float c_old = lds[C_OFF + uu * 64 + b];
                float c_new = f_g * c_old + i_g * g_g;
                float h_new = o_g * tanhf(c_new);
                lds[C_OFF + uu * 64 + b] = c_new;
                hn_buf[(u0 + uu) * 64 + b] = h_new;
                hvals[uu] = h_new;
            }
            if (t >= OUT0) {
                pout[((size_t)(t - OUT0) * NBLK + bid) * 64 + b] =
                    hvals[0] * wans[0] + hvals[1] * wans[1];
            }
        }

        grid_sync(bar, NBLK * (t + 1));
    }
}

// out[b][col] = sum over 512 block partials + bias.  (persist layout)
__global__ __launch_bounds__(256) void finalize_persist(
    const float* __restrict__ pout, const float* __restrict__ b_ans,
    float* __restrict__ out)
{
    __shared__ float r[256];
    int col = blockIdx.x;
    int tid = threadIdx.x;
    int b = tid & 63, q = tid >> 6;
    float s = 0.f;
    for (int i = q; i < NBLK; i += 4)
        s += pout[((size_t)col * NBLK + i) * 64 + b];
    r[tid] = s;
    __syncthreads();
    if (tid < 64)
        out[tid * NOUT + col] = r[tid] + r[64 + tid] + r[128 + tid] + r[192 + tid]
                              + b_ans[0];
}

// ===================== fallback path (round-3 proven) =====================
#define F_HEADOFF 4096
__global__ __launch_bounds__(1024, 4) void lstm_step_fb(
    const float* __restrict__ xT, const float* __restrict__ hT_in,
    float* __restrict__ hT_out, float* __restrict__ cT,
    const float* __restrict__ w_ih, const float* __restrict__ w_hh,
    const float* __restrict__ b_ih, const float* __restrict__ b_hh,
    const float* __restrict__ w_ans, float* __restrict__ pout, int t)
{
    __shared__ float lds[F_HEADOFF + 256];
    const int tid = threadIdx.x;
    const int bid = blockIdx.x;
    const int b   = tid & 63;
    const int ws  = __builtin_amdgcn_readfirstlane(tid >> 6);
    const int uu  = ws & 3;
    const int ksl = ws >> 2;
    const int u   = bid * 4 + uu;

    const float* wr_i[4];
    const float* wr_h[4];
    #pragma unroll
    for (int j = 0; j < 4; ++j) {
        wr_i[j] = w_ih + (size_t)(j * HID + u) * EMBED;
        wr_h[j] = w_hh + (size_t)(j * HID + u) * HID;
    }
    float acc[4];
    acc[0] = acc[1] = acc[2] = acc[3] = 0.f;
    {
        const float* xt = xT + (size_t)t * EMBED * 64;
        const int k0 = ksl * 128;
        #pragma unroll 4
        for (int g = 0; g < 32; ++g) {
            const int k = k0 + g * 4;
            float4 wv0 = *(const float4*)(wr_i[0] + k);
            float4 wv1 = *(const float4*)(wr_i[1] + k);
            float4 wv2 = *(const float4*)(wr_i[2] + k);
            float4 wv3 = *(const float4*)(wr_i[3] + k);
            float x0 = xt[(k + 0) * 64 + b];
            float x1 = xt[(k + 1) * 64 + b];
            float x2 = xt[(k + 2) * 64 + b];
            float x3 = xt[(k + 3) * 64 + b];
            acc[0] = fmaf(wv0.x, x0, acc[0]); acc[0] = fmaf(wv0.y, x1, acc[0]);
            acc[0] = fmaf(wv0.z, x2, acc[0]); acc[0] = fmaf(wv0.w, x3, acc[0]);
            acc[1] = fmaf(wv1.x, x0, acc[1]); acc[1] = fmaf(wv1.y, x1, acc[1]);
            acc[1] = fmaf(wv1.z, x2, acc[1]); acc[1] = fmaf(wv1.w, x3, acc[1]);
            acc[2] = fmaf(wv2.x, x0, acc[2]); acc[2] = fmaf(wv2.y, x1, acc[2]);
            acc[2] = fmaf(wv2.z, x2, acc[2]); acc[2] = fmaf(wv2.w, x3, acc[2]);
            acc[3] = fmaf(wv3.x, x0, acc[3]); acc[3] = fmaf(wv3.y, x1, acc[3]);
            acc[3] = fmaf(wv3.z, x2, acc[3]); acc[3] = fmaf(wv3.w, x3, acc[3]);
        }
    }
    {
        const int k0 = ksl * 256;
        #pragma unroll 4
        for (int g = 0; g < 64; ++g) {
            const int k = k0 + g * 4;
            float4 wv0 = *(const float4*)(wr_h[0] + k);
            float4 wv1 = *(const float4*)(wr_h[1] + k);
            float4 wv2 = *(const float4*)(wr_h[2] + k);
            float4 wv3 = *(const float4*)(wr_h[3] + k);
            float x0 = hT_in[(k + 0) * 64 + b];
            float x1 = hT_in[(k + 1) * 64 + b];
            float x2 = hT_in[(k + 2) * 64 + b];
            float x3 = hT_in[(k + 3) * 64 + b];
            acc[0] = fmaf(wv0.x, x0, acc[0]); acc[0] = fmaf(wv0.y, x1, acc[0]);
            acc[0] = fmaf(wv0.z, x2, acc[0]); acc[0] = fmaf(wv0.w, x3, acc[0]);
            acc[1] = fmaf(wv1.x, x0, acc[1]); acc[1] = fmaf(wv1.y, x1, acc[1]);
            acc[1] = fmaf(wv1.z, x2, acc[1]); acc[1] = fmaf(wv1.w, x3, acc[1]);
            acc[2] = fmaf(wv2.x, x0, acc[2]); acc[2] = fmaf(wv2.y, x1, acc[2]);
            acc[2] = fmaf(wv2.z, x2, acc[2]); acc[2] = fmaf(wv2.w, x3, acc[2]);
            acc[3] = fmaf(wv3.x, x0, acc[3]); acc[3] = fmaf(wv3.y, x1, acc[3]);
            acc[3] = fmaf(wv3.z, x2, acc[3]); acc[3] = fmaf(wv3.w, x3, acc[3]);
        }
    }
    #pragma unroll
    for (int j = 0; j < 4; ++j)
        lds[((ksl * 4 + uu) * 4 + j) * 64 + b] = acc[j];
    __syncthreads();
    if (tid < 256) {
        int b2  = tid & 63;
        int uu2 = tid >> 6;
        int u2  = bid * 4 + uu2;
        float s[4];
        #pragma unroll
        for (int j = 0; j < 4; ++j) {
            s[j] = lds[((0 * 4 + uu2) * 4 + j) * 64 + b2]
                 + lds[((1 * 4 + uu2) * 4 + j) * 64 + b2]
                 + lds[((2 * 4 + uu2) * 4 + j) * 64 + b2]
                 + lds[((3 * 4 + uu2) * 4 + j) * 64 + b2];
            int rj = j * HID + u2;
            s[j] += b_ih[rj] + b_hh[rj];
        }
        float ig = sigmoidf_(s[0]);
        float fg = sigmoidf_(s[1]);
        float gg = tanhf(s[2]);
        float og = sigmoidf_(s[3]);
        float cn = fg * cT[u2 * 64 + b2] + ig * gg;
        float hn = og * tanhf(cn);
        cT[u2 * 64 + b2]     = cn;
        hT_out[u2 * 64 + b2] = hn;
        lds[F_HEADOFF + uu2 * 64 + b2] = hn * w_ans[u2];
    }
    __syncthreads();
    if (t >= OUT0 && tid < 64) {
        float sum = lds[F_HEADOFF + tid]       + lds[F_HEADOFF + 64 + tid]
                  + lds[F_HEADOFF + 128 + tid] + lds[F_HEADOFF + 192 + tid];
        pout[((size_t)((t - OUT0) * 64 + tid)) * 256 + bid] = sum;
    }
}

__global__ __launch_bounds__(64) void finalize_fb(
    const float* __restrict__ pout, const float* __restrict__ b_ans,
    float* __restrict__ out)
{
    int blk  = blockIdx.x;
    int col  = blk >> 6;
    int bb   = blk & 63;
    int lane = threadIdx.x;
    const float* p = pout + (size_t)(col * 64 + bb) * 256;
    float s = p[lane] + p[lane + 64] + p[lane + 128] + p[lane + 192];
    #pragma unroll
    for (int off = 32; off > 0; off >>= 1) s += __shfl_down(s, off);
    if (lane == 0) out[bb * NOUT + col] = s + b_ans[0];
}

extern "C" void kernel_launch(void* const* d_in, const int* in_sizes, int n_in,
                              void* d_out, int out_size, void* d_ws, size_t ws_size,
                              hipStream_t stream)
{
    const int*   prob  = (const int*)  d_in[0];
    const float* embed = (const float*)d_in[2];
    const float* w_ih  = (const float*)d_in[3];
    const float* w_hh  = (const float*)d_in[4];
    const float* b_ih  = (const float*)d_in[5];
    const float* b_hh  = (const float*)d_in[6];
    const float* w_ans = (const float*)d_in[7];
    const float* b_ans = (const float*)d_in[8];
    const float* h0    = (const float*)d_in[9];
    const float* c0    = (const float*)d_in[10];

    float* ws   = (float*)d_ws;
    float* hT0  = ws;                          // 65536
    float* hT1  = ws + 65536;                  // 65536
    float* cT   = ws + 131072;                 // 65536
    float* pout = ws + 196608;                 // max(62*512*64, 62*64*256) = 2,031,616
    float* xT   = ws + 2228224;                // 127*512*64 = 4,161,536
    int*   bar  = (int*)(ws + 6389760);

    hipMemsetAsync(bar, 0, sizeof(int), stream);
    init_state<<<256, 256, 0, stream>>>(h0, c0, hT0, cT);
    embed_transpose<<<NSTEP, 256, 0, stream>>>(prob, embed, xT);

    void* args[] = {
        (void*)&xT, (void*)&hT0, (void*)&hT1, (void*)&cT,
        (void*)&w_ih, (void*)&w_hh, (void*)&b_ih, (void*)&b_hh,
        (void*)&w_ans, (void*)&pout, (void*)&bar
    };
    hipError_t err = hipLaunchCooperativeKernel((const void*)lstm_persist,
                                                dim3(NBLK), dim3(NTHR),
                                                args, 0, stream);
    if (err == hipSuccess) {
        finalize_persist<<<NOUT, 256, 0, stream>>>(pout, b_ans, (float*)d_out);
    } else {
        // fallback: proven per-step path
        for (int t = 0; t < NSTEP; ++t) {
            float* hin  = (t & 1) ? hT1 : hT0;
            float* hout = (t & 1) ? hT0 : hT1;
            lstm_step_fb<<<256, 1024, 0, stream>>>(xT, hin, hout, cT, w_ih, w_hh,
                                                   b_ih, b_hh, w_ans, pout, t);
        }
        finalize_fb<<<NOUT * 64, 64, 0, stream>>>(pout, b_ans, (float*)d_out);
    }
}

// Round 7
// 2654.625 us; speedup vs baseline: 8.9631x; 2.4333x over previous
//
#include <hip/hip_runtime.h>
#include <math.h>

#define BATCH   64
#define SEQLEN  128
#define EMBED   512
#define HID     1024
#define NSTEP   127
#define OUT0    65
#define NOUT    62
#define NBLK    512
#define NTHR    512

// LDS layout (floats) for lstm_persist:
//   wlds [uu 2][k 1536][gate 4] = 12288 @ 0        (48 KB, persistent)
//   red  phaseA 2048 @ 12288, phaseB 1024 @ 14336, phaseC 512 @ 15360
//   c    128 @ 15872
#define REDA_OFF 12288
#define REDB_OFF 14336
#define REDC_OFF 15360
#define C_OFF    15872
#define LDS_FLOATS 16000   // 64000 B

__device__ __forceinline__ float sigmoidf_(float x) { return 1.f / (1.f + expf(-x)); }

// Transpose h0/c0 ([b][u]) into [u][b] working layout.
__global__ __launch_bounds__(256) void init_state(
    const float* __restrict__ h0, const float* __restrict__ c0,
    float* __restrict__ hT, float* __restrict__ cT)
{
    int id = blockIdx.x * 256 + threadIdx.x;   // u*64+b
    int u = id >> 6, b = id & 63;
    hT[id] = h0[b * HID + u];
    cT[id] = c0[b * HID + u];
}

// Build xT[t][k][b] = embed[prob[b][t]][k] (one-time gather+transpose).
__global__ __launch_bounds__(256) void embed_transpose(
    const int* __restrict__ prob, const float* __restrict__ embed,
    float* __restrict__ xT)
{
    __shared__ float xe[64 * 132];
    int t = blockIdx.x;
    int tid = threadIdx.x;
    for (int kt = 0; kt < 4; ++kt) {
        #pragma unroll
        for (int i = 0; i < 8; ++i) {
            int id = tid + i * 256;
            int b  = id >> 5;
            int k4 = id & 31;
            int tok = prob[b * SEQLEN + t];
            float4 v = *(const float4*)(embed + (size_t)tok * EMBED + kt * 128 + k4 * 4);
            *(float4*)(&xe[b * 132 + k4 * 4]) = v;
        }
        __syncthreads();
        #pragma unroll
        for (int i = 0; i < 8; ++i) {
            int id = tid + i * 256;
            int kl = id >> 4;
            int b4 = id & 15;
            float4 v;
            v.x = xe[(b4 * 4 + 0) * 132 + kl];
            v.y = xe[(b4 * 4 + 1) * 132 + kl];
            v.z = xe[(b4 * 4 + 2) * 132 + kl];
            v.w = xe[(b4 * 4 + 3) * 132 + kl];
            *(float4*)(&xT[((size_t)t * EMBED + kt * 128 + kl) * 64 + b4 * 4]) = v;
        }
        __syncthreads();
    }
}

// ===================== persistent path =====================
// 512 blocks x 512 threads (2 blocks/CU). Block owns units u0, u0+1.
// Wave ksl: x-slice 64 k's, h-slice 128 k's. Lane = batch.
// Cross-step h exchange via relaxed agent-scope atomics (sc1 write-through /
// L2-bypass reads) -> NO cache invalidates, x stays L2-resident.
// Barrier: 8 striped arrive counters -> super counter -> go flag; workers
// spin read-only on go. x-part of step t computed BEFORE waiting on go(t).
__global__ __launch_bounds__(NTHR, 4) void lstm_persist(
    const float* __restrict__ xT, float* __restrict__ hb0, float* __restrict__ hb1,
    const float* __restrict__ cT,
    const float* __restrict__ w_ih, const float* __restrict__ w_hh,
    const float* __restrict__ b_ih, const float* __restrict__ b_hh,
    const float* __restrict__ w_ans, float* __restrict__ pout,
    int* __restrict__ bar)
{
    __shared__ float lds[LDS_FLOATS];
    const int tid = threadIdx.x;
    const int bid = blockIdx.x;
    const int b   = tid & 63;
    const int ksl = __builtin_amdgcn_readfirstlane(tid >> 6);  // 0..7
    const int u0  = bid * 2;

    int* cnt  = bar + (bid & 7) * 32;   // 8 stripes, 128 B apart
    int* scnt = bar + 256;
    int* go   = bar + 288;

    // one-time: weights -> LDS  [uu][k][gate]
    for (int idx = tid; idx < 12288; idx += NTHR) {
        int r  = idx / 1536;          // 0..7
        int k  = idx - r * 1536;
        int uu = r & 1, gate = r >> 1;
        int row = gate * HID + u0 + uu;
        float v = (k < EMBED) ? w_ih[(size_t)row * EMBED + k]
                              : w_hh[(size_t)row * HID + (k - EMBED)];
        lds[(uu * 1536 + k) * 4 + gate] = v;
    }
    if (tid < 128) lds[C_OFF + tid] = cT[u0 * 64 + tid];

    float bias[2][4], wans[2];
    #pragma unroll
    for (int uu = 0; uu < 2; ++uu) {
        #pragma unroll
        for (int j = 0; j < 4; ++j) {
            int rj = j * HID + u0 + uu;
            bias[uu][j] = b_ih[rj] + b_hh[rj];
        }
        wans[uu] = w_ans[u0 + uu];
    }
    __syncthreads();

    for (int t = 0; t < NSTEP; ++t) {
        const float* xt = xT + (size_t)t * EMBED * 64;
        const float* ht = (t & 1) ? hb1 : hb0;
        float* hn_buf   = (t & 1) ? hb0 : hb1;

        float acc[2][4];
        #pragma unroll
        for (int uu = 0; uu < 2; ++uu)
            #pragma unroll
            for (int j = 0; j < 4; ++j) acc[uu][j] = 0.f;

        // ---- x phase (k in [ksl*64, ksl*64+64), L2-cached loads) ----
        const int kx0 = ksl * 64;
        #pragma unroll 4
        for (int g = 0; g < 16; ++g) {
            const int k = kx0 + g * 4;
            float xv[4];
            #pragma unroll
            for (int i = 0; i < 4; ++i) xv[i] = xt[(size_t)(k + i) * 64 + b];
            #pragma unroll
            for (int i = 0; i < 4; ++i) {
                float4 wa = *(const float4*)&lds[(0 * 1536 + k + i) * 4];
                float4 wb = *(const float4*)&lds[(1 * 1536 + k + i) * 4];
                acc[0][0] = fmaf(wa.x, xv[i], acc[0][0]);
                acc[0][1] = fmaf(wa.y, xv[i], acc[0][1]);
                acc[0][2] = fmaf(wa.z, xv[i], acc[0][2]);
                acc[0][3] = fmaf(wa.w, xv[i], acc[0][3]);
                acc[1][0] = fmaf(wb.x, xv[i], acc[1][0]);
                acc[1][1] = fmaf(wb.y, xv[i], acc[1][1]);
                acc[1][2] = fmaf(wb.z, xv[i], acc[1][2]);
                acc[1][3] = fmaf(wb.w, xv[i], acc[1][3]);
            }
        }

        // ---- wait for h(t-1): spin read-only on go (no invalidates) ----
        if (t > 0) {
            if (tid == 0) {
                while (__hip_atomic_load(go, __ATOMIC_RELAXED,
                                         __HIP_MEMORY_SCOPE_AGENT) < t)
                    __builtin_amdgcn_s_sleep(1);
            }
            __syncthreads();
        }

        // ---- h phase (k in [ksl*128, ksl*128+128), agent-scope loads) ----
        const int kh0 = ksl * 128;
        #pragma unroll 4
        for (int g = 0; g < 32; ++g) {
            const int kh = kh0 + g * 4;
            float hv[4];
            #pragma unroll
            for (int i = 0; i < 4; ++i)
                hv[i] = __hip_atomic_load(&ht[(size_t)(kh + i) * 64 + b],
                                          __ATOMIC_RELAXED, __HIP_MEMORY_SCOPE_AGENT);
            #pragma unroll
            for (int i = 0; i < 4; ++i) {
                const int kw = EMBED + kh + i;
                float4 wa = *(const float4*)&lds[(0 * 1536 + kw) * 4];
                float4 wb = *(const float4*)&lds[(1 * 1536 + kw) * 4];
                acc[0][0] = fmaf(wa.x, hv[i], acc[0][0]);
                acc[0][1] = fmaf(wa.y, hv[i], acc[0][1]);
                acc[0][2] = fmaf(wa.z, hv[i], acc[0][2]);
                acc[0][3] = fmaf(wa.w, hv[i], acc[0][3]);
                acc[1][0] = fmaf(wb.x, hv[i], acc[1][0]);
                acc[1][1] = fmaf(wb.y, hv[i], acc[1][1]);
                acc[1][2] = fmaf(wb.z, hv[i], acc[1][2]);
                acc[1][3] = fmaf(wb.w, hv[i], acc[1][3]);
            }
        }

        // ---- tree reduction 8 -> 4 -> 2 -> 1 waves ----
        if (ksl >= 4) {
            #pragma unroll
            for (int uu = 0; uu < 2; ++uu)
                #pragma unroll
                for (int j = 0; j < 4; ++j)
                    lds[REDA_OFF + (((ksl - 4) * 8) + uu * 4 + j) * 64 + b] = acc[uu][j];
        }
        __syncthreads();
        if (ksl < 4) {
            #pragma unroll
            for (int uu = 0; uu < 2; ++uu)
                #pragma unroll
                for (int j = 0; j < 4; ++j)
                    acc[uu][j] += lds[REDA_OFF + ((ksl * 8) + uu * 4 + j) * 64 + b];
        }
        if (ksl == 2 || ksl == 3) {
            #pragma unroll
            for (int uu = 0; uu < 2; ++uu)
                #pragma unroll
                for (int j = 0; j < 4; ++j)
                    lds[REDB_OFF + (((ksl - 2) * 8) + uu * 4 + j) * 64 + b] = acc[uu][j];
        }
        __syncthreads();
        if (ksl < 2) {
            #pragma unroll
            for (int uu = 0; uu < 2; ++uu)
                #pragma unroll
                for (int j = 0; j < 4; ++j)
                    acc[uu][j] += lds[REDB_OFF + ((ksl * 8) + uu * 4 + j) * 64 + b];
        }
        if (ksl == 1) {
            #pragma unroll
            for (int uu = 0; uu < 2; ++uu)
                #pragma unroll
                for (int j = 0; j < 4; ++j)
                    lds[REDC_OFF + (uu * 4 + j) * 64 + b] = acc[uu][j];
        }
        __syncthreads();
        if (ksl == 0) {
            float hvals[2];
            #pragma unroll
            for (int uu = 0; uu < 2; ++uu) {
                #pragma unroll
                for (int j = 0; j < 4; ++j)
                    acc[uu][j] += lds[REDC_OFF + (uu * 4 + j) * 64 + b];
                float i_g = sigmoidf_(acc[uu][0] + bias[uu][0]);
                float f_g = sigmoidf_(acc[uu][1] + bias[uu][1]);
                float g_g = tanhf   (acc[uu][2] + bias[uu][2]);
                float o_g = sigmoidf_(acc[uu][3] + bias[uu][3]);
                float c_old = lds[C_OFF + uu * 64 + b];
                float c_new = f_g * c_old + i_g * g_g;
                float h_new = o_g * tanhf(c_new);
                lds[C_OFF + uu * 64 + b] = c_new;
                __hip_atomic_store(&hn_buf[(u0 + uu) * 64 + b], h_new,
                                   __ATOMIC_RELAXED, __HIP_MEMORY_SCOPE_AGENT);
                hvals[uu] = h_new;
            }
            if (t >= OUT0) {
                pout[((size_t)(t - OUT0) * NBLK + bid) * 64 + b] =
                    hvals[0] * wans[0] + hvals[1] * wans[1];
            }
        }

        if (t == NSTEP - 1) break;   // no barrier after last step

        // ---- arrive: striped counters -> super -> go (last arriver publishes) ----
        __syncthreads();   // drains all waves' stores (vmcnt 0) before arrive
        if (tid == 0) {
            int r = __hip_atomic_fetch_add(cnt, 1, __ATOMIC_RELAXED,
                                           __HIP_MEMORY_SCOPE_AGENT);
            if (r == 64 * (t + 1) - 1) {
                int s2 = __hip_atomic_fetch_add(scnt, 1, __ATOMIC_RELAXED,
                                                __HIP_MEMORY_SCOPE_AGENT);
                if (s2 == 8 * (t + 1) - 1)
                    __hip_atomic_store(go, t + 1, __ATOMIC_RELAXED,
                                       __HIP_MEMORY_SCOPE_AGENT);
            }
        }
    }
}

// out[b][col] = sum over 512 block partials + bias.  (persist layout)
__global__ __launch_bounds__(256) void finalize_persist(
    const float* __restrict__ pout, const float* __restrict__ b_ans,
    float* __restrict__ out)
{
    __shared__ float r[256];
    int col = blockIdx.x;
    int tid = threadIdx.x;
    int b = tid & 63, q = tid >> 6;
    float s = 0.f;
    for (int i = q; i < NBLK; i += 4)
        s += pout[((size_t)col * NBLK + i) * 64 + b];
    r[tid] = s;
    __syncthreads();
    if (tid < 64)
        out[tid * NOUT + col] = r[tid] + r[64 + tid] + r[128 + tid] + r[192 + tid]
                              + b_ans[0];
}

// ===================== fallback path (round-3 proven) =====================
#define F_HEADOFF 4096
__global__ __launch_bounds__(1024, 4) void lstm_step_fb(
    const float* __restrict__ xT, const float* __restrict__ hT_in,
    float* __restrict__ hT_out, float* __restrict__ cT,
    const float* __restrict__ w_ih, const float* __restrict__ w_hh,
    const float* __restrict__ b_ih, const float* __restrict__ b_hh,
    const float* __restrict__ w_ans, float* __restrict__ pout, int t)
{
    __shared__ float lds[F_HEADOFF + 256];
    const int tid = threadIdx.x;
    const int bid = blockIdx.x;
    const int b   = tid & 63;
    const int ws  = __builtin_amdgcn_readfirstlane(tid >> 6);
    const int uu  = ws & 3;
    const int ksl = ws >> 2;
    const int u   = bid * 4 + uu;

    const float* wr_i[4];
    const float* wr_h[4];
    #pragma unroll
    for (int j = 0; j < 4; ++j) {
        wr_i[j] = w_ih + (size_t)(j * HID + u) * EMBED;
        wr_h[j] = w_hh + (size_t)(j * HID + u) * HID;
    }
    float acc[4];
    acc[0] = acc[1] = acc[2] = acc[3] = 0.f;
    {
        const float* xt = xT + (size_t)t * EMBED * 64;
        const int k0 = ksl * 128;
        #pragma unroll 4
        for (int g = 0; g < 32; ++g) {
            const int k = k0 + g * 4;
            float4 wv0 = *(const float4*)(wr_i[0] + k);
            float4 wv1 = *(const float4*)(wr_i[1] + k);
            float4 wv2 = *(const float4*)(wr_i[2] + k);
            float4 wv3 = *(const float4*)(wr_i[3] + k);
            float x0 = xt[(k + 0) * 64 + b];
            float x1 = xt[(k + 1) * 64 + b];
            float x2 = xt[(k + 2) * 64 + b];
            float x3 = xt[(k + 3) * 64 + b];
            acc[0] = fmaf(wv0.x, x0, acc[0]); acc[0] = fmaf(wv0.y, x1, acc[0]);
            acc[0] = fmaf(wv0.z, x2, acc[0]); acc[0] = fmaf(wv0.w, x3, acc[0]);
            acc[1] = fmaf(wv1.x, x0, acc[1]); acc[1] = fmaf(wv1.y, x1, acc[1]);
            acc[1] = fmaf(wv1.z, x2, acc[1]); acc[1] = fmaf(wv1.w, x3, acc[1]);
            acc[2] = fmaf(wv2.x, x0, acc[2]); acc[2] = fmaf(wv2.y, x1, acc[2]);
            acc[2] = fmaf(wv2.z, x2, acc[2]); acc[2] = fmaf(wv2.w, x3, acc[2]);
            acc[3] = fmaf(wv3.x, x0, acc[3]); acc[3] = fmaf(wv3.y, x1, acc[3]);
            acc[3] = fmaf(wv3.z, x2, acc[3]); acc[3] = fmaf(wv3.w, x3, acc[3]);
        }
    }
    {
        const int k0 = ksl * 256;
        #pragma unroll 4
        for (int g = 0; g < 64; ++g) {
            const int k = k0 + g * 4;
            float4 wv0 = *(const float4*)(wr_h[0] + k);
            float4 wv1 = *(const float4*)(wr_h[1] + k);
            float4 wv2 = *(const float4*)(wr_h[2] + k);
            float4 wv3 = *(const float4*)(wr_h[3] + k);
            float x0 = hT_in[(k + 0) * 64 + b];
            float x1 = hT_in[(k + 1) * 64 + b];
            float x2 = hT_in[(k + 2) * 64 + b];
            float x3 = hT_in[(k + 3) * 64 + b];
            acc[0] = fmaf(wv0.x, x0, acc[0]); acc[0] = fmaf(wv0.y, x1, acc[0]);
            acc[0] = fmaf(wv0.z, x2, acc[0]); acc[0] = fmaf(wv0.w, x3, acc[0]);
            acc[1] = fmaf(wv1.x, x0, acc[1]); acc[1] = fmaf(wv1.y, x1, acc[1]);
            acc[1] = fmaf(wv1.z, x2, acc[1]); acc[1] = fmaf(wv1.w, x3, acc[1]);
            acc[2] = fmaf(wv2.x, x0, acc[2]); acc[2] = fmaf(wv2.y, x1, acc[2]);
            acc[2] = fmaf(wv2.z, x2, acc[2]); acc[2] = fmaf(wv2.w, x3, acc[2]);
            acc[3] = fmaf(wv3.x, x0, acc[3]); acc[3] = fmaf(wv3.y, x1, acc[3]);
            acc[3] = fmaf(wv3.z, x2, acc[3]); acc[3] = fmaf(wv3.w, x3, acc[3]);
        }
    }
    #pragma unroll
    for (int j = 0; j < 4; ++j)
        lds[((ksl * 4 + uu) * 4 + j) * 64 + b] = acc[j];
    __syncthreads();
    if (tid < 256) {
        int b2  = tid & 63;
        int uu2 = tid >> 6;
        int u2  = bid * 4 + uu2;
        float s[4];
        #pragma unroll
        for (int j = 0; j < 4; ++j) {
            s[j] = lds[((0 * 4 + uu2) * 4 + j) * 64 + b2]
                 + lds[((1 * 4 + uu2) * 4 + j) * 64 + b2]
                 + lds[((2 * 4 + uu2) * 4 + j) * 64 + b2]
                 + lds[((3 * 4 + uu2) * 4 + j) * 64 + b2];
            int rj = j * HID + u2;
            s[j] += b_ih[rj] + b_hh[rj];
        }
        float ig = sigmoidf_(s[0]);
        float fg = sigmoidf_(s[1]);
        float gg = tanhf(s[2]);
        float og = sigmoidf_(s[3]);
        float cn = fg * cT[u2 * 64 + b2] + ig * gg;
        float hn = og * tanhf(cn);
        cT[u2 * 64 + b2]     = cn;
        hT_out[u2 * 64 + b2] = hn;
        lds[F_HEADOFF + uu2 * 64 + b2] = hn * w_ans[u2];
    }
    __syncthreads();
    if (t >= OUT0 && tid < 64) {
        float sum = lds[F_HEADOFF + tid]       + lds[F_HEADOFF + 64 + tid]
                  + lds[F_HEADOFF + 128 + tid] + lds[F_HEADOFF + 192 + tid];
        pout[((size_t)((t - OUT0) * 64 + tid)) * 256 + bid] = sum;
    }
}

__global__ __launch_bounds__(64) void finalize_fb(
    const float* __restrict__ pout, const float* __restrict__ b_ans,
    float* __restrict__ out)
{
    int blk  = blockIdx.x;
    int col  = blk >> 6;
    int bb   = blk & 63;
    int lane = threadIdx.x;
    const float* p = pout + (size_t)(col * 64 + bb) * 256;
    float s = p[lane] + p[lane + 64] + p[lane + 128] + p[lane + 192];
    #pragma unroll
    for (int off = 32; off > 0; off >>= 1) s += __shfl_down(s, off);
    if (lane == 0) out[bb * NOUT + col] = s + b_ans[0];
}

extern "C" void kernel_launch(void* const* d_in, const int* in_sizes, int n_in,
                              void* d_out, int out_size, void* d_ws, size_t ws_size,
                              hipStream_t stream)
{
    const int*   prob  = (const int*)  d_in[0];
    const float* embed = (const float*)d_in[2];
    const float* w_ih  = (const float*)d_in[3];
    const float* w_hh  = (const float*)d_in[4];
    const float* b_ih  = (const float*)d_in[5];
    const float* b_hh  = (const float*)d_in[6];
    const float* w_ans = (const float*)d_in[7];
    const float* b_ans = (const float*)d_in[8];
    const float* h0    = (const float*)d_in[9];
    const float* c0    = (const float*)d_in[10];

    float* ws   = (float*)d_ws;
    float* hT0  = ws;                          // 65536
    float* hT1  = ws + 65536;                  // 65536
    float* cT   = ws + 131072;                 // 65536
    float* pout = ws + 196608;                 // 2,031,616
    float* xT   = ws + 2228224;                // 4,161,536
    int*   bar  = (int*)(ws + 6389760);        // 2048 B barrier region

    hipMemsetAsync(bar, 0, 2048, stream);
    init_state<<<256, 256, 0, stream>>>(h0, c0, hT0, cT);
    embed_transpose<<<NSTEP, 256, 0, stream>>>(prob, embed, xT);

    void* args[] = {
        (void*)&xT, (void*)&hT0, (void*)&hT1, (void*)&cT,
        (void*)&w_ih, (void*)&w_hh, (void*)&b_ih, (void*)&b_hh,
        (void*)&w_ans, (void*)&pout, (void*)&bar
    };
    hipError_t err = hipLaunchCooperativeKernel((const void*)lstm_persist,
                                                dim3(NBLK), dim3(NTHR),
                                                args, 0, stream);
    if (err == hipSuccess) {
        finalize_persist<<<NOUT, 256, 0, stream>>>(pout, b_ans, (float*)d_out);
    } else {
        // fallback: proven per-step path
        for (int t = 0; t < NSTEP; ++t) {
            float* hin  = (t & 1) ? hT1 : hT0;
            float* hout = (t & 1) ? hT0 : hT1;
            lstm_step_fb<<<256, 1024, 0, stream>>>(xT, hin, hout, cT, w_ih, w_hh,
                                                   b_ih, b_hh, w_ans, pout, t);
        }
        finalize_fb<<<NOUT * 64, 64, 0, stream>>>(pout, b_ans, (float*)d_out);
    }
}